// Round 2
// baseline (780.945 us; speedup 1.0000x reference)
//
#include <hip/hip_runtime.h>
#include <cstdint>
#include <cstddef>

#define T_SEQ 512
#define BATCH 64
#define IN_SZ 512
#define HID   1024
#define BH    (BATCH*HID)      /* 65536 */
#define M_TOT (T_SEQ*BATCH)    /* 32768 */

typedef float f32x4 __attribute__((ext_vector_type(4)));
typedef _Float16 f16x8 __attribute__((ext_vector_type(8)));

__device__ inline unsigned short f2h(float f){
  union { _Float16 h; unsigned short u; } v;
  v.h = (_Float16)f;            // RTNE
  return v.u;
}
__device__ inline float h2f(unsigned short s){
  union { unsigned short u; _Float16 h; } v; v.u = s;
  return (float)v.h;
}
__device__ inline float ldv(const float* p){ return *p; }
__device__ inline float ldv(const unsigned short* p){ return h2f(*p); }

__device__ inline float sigm_f(float x){ return 1.f/(1.f + __expf(-x)); }
__device__ inline float tanh_f(float x){ float e = __expf(2.f*x); return 1.f - 2.f/(e + 1.f); }

// async global->LDS, 16B per lane; lds base must be wave-uniform
__device__ inline void async16(const void* g, void* l){
  __builtin_amdgcn_global_load_lds(
      (__attribute__((address_space(1))) void*)g,
      (__attribute__((address_space(3))) void*)l,
      16, 0, 0);
}

// ---------- fp32 -> fp16 conversion (float4 vectorized) ----------
__global__ __launch_bounds__(256) void cvt_f16(const float* __restrict__ in,
                                               unsigned short* __restrict__ out, int n4){
  int i = blockIdx.x*256 + threadIdx.x;
  if (i >= n4) return;
  float4 v = ((const float4*)in)[i];
  ushort4 o;
  o.x = f2h(v.x); o.y = f2h(v.y); o.z = f2h(v.z); o.w = f2h(v.w);
  ((ushort4*)out)[i] = o;
}

// ---------- fused 3-projection GEMM (fp16 MFMA) ----------
// A = x_f16 [M_TOT, IN_SZ] row-major; B^T = U [HID, IN_SZ] row-major.
// 128x128 tile, BK=64, 4 waves each computing a 64x64 quadrant (4x4 MFMA 16x16x32 tiles).
// LDS layout: 16B chunks, chunk(row, o_l) with o_l = o_g ^ (row&7)  (XOR swizzle so
// ds_read_b128 fragment reads are conflict-free within each 8-lane group).
__global__ __launch_bounds__(256) void gemm3(
    const unsigned short* __restrict__ xb,
    const unsigned short* __restrict__ U0,
    const unsigned short* __restrict__ U1,
    const unsigned short* __restrict__ U2,
    const float* __restrict__ b0, const float* __restrict__ b1, const float* __restrict__ b2,
    void* out0, void* out1, float* out2, int store_f16)
{
  __shared__ uint4 smem[2048];   // 32 KB: A chunks [0,1024), B chunks [1024,2048)
  const int tid  = threadIdx.x;
  const int wave = tid >> 6, lane = tid & 63;
  const int quad = lane >> 4, l16 = lane & 15;
  const int nb = blockIdx.x;   // 0..7
  const int mb = blockIdx.y;   // 0..255
  const int z  = blockIdx.z;   // 0..2
  const int m0 = mb * 128, n0 = nb * 128;
  const unsigned short* Um = (z==0) ? U0 : (z==1) ? U1 : U2;
  const float* bias        = (z==0) ? b0 : (z==1) ? b1 : b2;
  const int wm = wave >> 1, wn = wave & 1;

  const f32x4 zf = {0.f, 0.f, 0.f, 0.f};
  f32x4 acc[4][4];
#pragma unroll
  for (int i=0;i<4;i++)
#pragma unroll
    for (int j=0;j<4;j++) acc[i][j] = zf;

  const uint4* ldsA = smem;
  const uint4* ldsB = smem + 1024;

  for (int k0 = 0; k0 < IN_SZ; k0 += 64) {
    // stage A and B tiles: each wave issues 8 x (64 lanes x 16B) loads
#pragma unroll
    for (int j = 0; j < 4; j++) {
      int c   = (wave*4 + j)*64 + lane;
      int row = c >> 3;
      int og  = (c & 7) ^ (row & 7);
      const unsigned short* ga = xb + (size_t)(m0 + row)*IN_SZ + k0 + og*8;
      const unsigned short* gb = Um + (size_t)(n0 + row)*IN_SZ + k0 + og*8;
      async16(ga, (void*)(smem + (size_t)(wave*4 + j)*64));
      async16(gb, (void*)(smem + 1024 + (size_t)(wave*4 + j)*64));
    }
    __syncthreads();   // drains vmcnt before ds_read

#pragma unroll
    for (int ks8 = 0; ks8 < 8; ks8 += 4) {   // two K=32 steps
      f16x8 af[4], bfr[4];
#pragma unroll
      for (int im = 0; im < 4; im++){
        int row = wm*64 + im*16 + l16;
        int ch  = row*8 + ((ks8 + quad) ^ (row & 7));
        af[im] = *(const f16x8*)(ldsA + ch);
      }
#pragma unroll
      for (int in = 0; in < 4; in++){
        int row = wn*64 + in*16 + l16;
        int ch  = row*8 + ((ks8 + quad) ^ (row & 7));
        bfr[in] = *(const f16x8*)(ldsB + ch);
      }
#pragma unroll
      for (int im = 0; im < 4; im++)
#pragma unroll
        for (int in = 0; in < 4; in++)
          acc[im][in] = __builtin_amdgcn_mfma_f32_16x16x32_f16(af[im], bfr[in], acc[im][in], 0, 0, 0);
    }
    __syncthreads();
  }

  // epilogue: C/D layout col = lane&15, row = quad*4 + reg
  float bv[4];
#pragma unroll
  for (int in = 0; in < 4; in++) bv[in] = bias[n0 + wn*64 + in*16 + l16];

#pragma unroll
  for (int im = 0; im < 4; im++){
#pragma unroll
    for (int r = 0; r < 4; r++){
      int row = m0 + wm*64 + im*16 + quad*4 + r;
      size_t rb = (size_t)row * HID;
#pragma unroll
      for (int in = 0; in < 4; in++){
        int col = n0 + wn*64 + in*16 + l16;
        float v = acc[im][in][r] + bv[in];
        if (z == 2) {
          out2[rb + col] = v;
        } else {
          void* op = (z==0) ? out0 : out1;
          if (store_f16) ((unsigned short*)op)[rb + col] = f2h(v);
          else           ((float*)op)[rb + col] = v;
        }
      }
    }
  }
}

// ---------- elementwise recurrence: one thread per (b,h), loop over t ----------
template <typename LT>
__global__ __launch_bounds__(256) void scan_k(
    const LT* __restrict__ pc, const LT* __restrict__ pa,
    float* __restrict__ y,                 // [T, BH]: holds ph on input, y on output (in place)
    const float* __restrict__ h0, const float* __restrict__ wc, const float* __restrict__ wa,
    float* __restrict__ hlast)
{
  const int idx  = blockIdx.x * 256 + threadIdx.x;   // 0..65535
  const int hidx = idx & (HID - 1);
  float h = h0[idx];
  const float wcv = wc[hidx], wav = wa[hidx];

  constexpr int D = 4;   // prefetch depth: 4 iters x 3 loads x 4B x 64 lanes = 3KB/wave in flight
  float pcb[D], pab[D], phb[D];
#pragma unroll
  for (int i = 0; i < D; i++){
    size_t b = (size_t)i*BH + idx;
    pcb[i] = ldv(pc + b); pab[i] = ldv(pa + b); phb[i] = y[b];
  }

#pragma unroll 4
  for (int t = 0; t < T_SEQ; t++){
    int s = t & (D - 1);
    float pcv = pcb[s], pav = pab[s], phv = phb[s];
    int tn = t + D;
    if (tn < T_SEQ){
      size_t b = (size_t)tn*BH + idx;
      pcb[s] = ldv(pc + b); pab[s] = ldv(pa + b); phb[s] = y[b];
    }
    float c  = sigm_f(pcv + wcv*h);
    float a  = 1.f + tanh_f(pav + wav*h);
    float hc = tanh_f(phv + a*h);
    h = c*h + (1.f - c)*hc;
    y[(size_t)t*BH + idx] = h;
  }
  hlast[idx] = h;
}

extern "C" void kernel_launch(void* const* d_in, const int* in_sizes, int n_in,
                              void* d_out, int out_size, void* d_ws, size_t ws_size,
                              hipStream_t stream)
{
  const float* x  = (const float*)d_in[0];
  const float* h0 = (const float*)d_in[1];
  const float* Uc = (const float*)d_in[2];
  const float* wc = (const float*)d_in[3];
  const float* bc = (const float*)d_in[4];
  const float* Ua = (const float*)d_in[5];
  const float* wa = (const float*)d_in[6];
  const float* ba = (const float*)d_in[7];
  const float* Uh = (const float*)d_in[8];
  const float* bh = (const float*)d_in[9];

  float* y     = (float*)d_out;                 // [T,B,H]
  float* hlast = y + (size_t)T_SEQ * BH;        // [B,H]

  const size_t szP32 = (size_t)T_SEQ * BH * 4;  // 134,217,728 B per projection
  const size_t szP16 = szP32 / 2;
  const size_t szX16 = (size_t)M_TOT * IN_SZ * 2;  // 33,554,432 B
  const size_t szU16 = (size_t)HID * IN_SZ * 2;    // 1,048,576 B

  const bool f32p = ws_size >= 2*szP32 + szX16 + 3*szU16;

  char* w = (char*)d_ws;
  void *pcp, *pap; unsigned short *xb, *U0b;
  if (f32p){
    pcp = (void*)w;
    pap = (void*)(w + szP32);
    xb  = (unsigned short*)(w + 2*szP32);
    U0b = (unsigned short*)(w + 2*szP32 + szX16);
  } else {
    pcp = (void*)w;
    pap = (void*)(w + szP16);
    xb  = (unsigned short*)(w + 2*szP16);
    U0b = (unsigned short*)(w + 2*szP16 + szX16);
  }
  unsigned short* U1b = U0b + szU16/2;
  unsigned short* U2b = U1b + szU16/2;

  // convert inputs to fp16
  {
    int n4 = M_TOT*IN_SZ/4;
    cvt_f16<<<(n4 + 255)/256, 256, 0, stream>>>(x, xb, n4);
    int u4 = HID*IN_SZ/4;
    cvt_f16<<<(u4 + 255)/256, 256, 0, stream>>>(Uc, U0b, u4);
    cvt_f16<<<(u4 + 255)/256, 256, 0, stream>>>(Ua, U1b, u4);
    cvt_f16<<<(u4 + 255)/256, 256, 0, stream>>>(Uh, U2b, u4);
  }

  // three projections: z=0 -> pc(ws), z=1 -> pa(ws), z=2 -> ph (into d_out y region)
  gemm3<<<dim3(8, 256, 3), 256, 0, stream>>>(xb, U0b, U1b, U2b, bc, ba, bh,
                                             pcp, pap, y, f32p ? 0 : 1);

  if (f32p)
    scan_k<float><<<BH/256, 256, 0, stream>>>((const float*)pcp, (const float*)pap,
                                              y, h0, wc, wa, hlast);
  else
    scan_k<unsigned short><<<BH/256, 256, 0, stream>>>((const unsigned short*)pcp,
                                                       (const unsigned short*)pap,
                                                       y, h0, wc, wa, hlast);
}

// Round 3
// 468.219 us; speedup vs baseline: 1.6679x; 1.6679x over previous
//
#include <hip/hip_runtime.h>
#include <cstdint>
#include <cstddef>

#define T_SEQ 512
#define BATCH 64
#define IN_SZ 512
#define HID   1024
#define BH    (BATCH*HID)      /* 65536 */
#define M_TOT (T_SEQ*BATCH)    /* 32768 */
#define D_CH  16               /* scan chunk depth */

typedef float f32x4 __attribute__((ext_vector_type(4)));
typedef _Float16 f16x8 __attribute__((ext_vector_type(8)));

__device__ inline unsigned short f2h(float f){
  union { _Float16 h; unsigned short u; } v;
  v.h = (_Float16)f;            // RTNE
  return v.u;
}
__device__ inline float h2f(unsigned short s){
  union { unsigned short u; _Float16 h; } v; v.u = s;
  return (float)v.h;
}

__device__ inline float sigm_f(float x){ return 1.f/(1.f + __expf(-x)); }
__device__ inline float tanh_f(float x){ float e = __expf(2.f*x); return 1.f - 2.f/(e + 1.f); }

// async global->LDS, 16B per lane; lds base must be wave-uniform
__device__ inline void async16(const void* g, void* l){
  __builtin_amdgcn_global_load_lds(
      (__attribute__((address_space(1))) void*)g,
      (__attribute__((address_space(3))) void*)l,
      16, 0, 0);
}

// ---------- fp32 -> fp16 conversion (float4 vectorized) ----------
__global__ __launch_bounds__(256) void cvt_f16(const float* __restrict__ in,
                                               unsigned short* __restrict__ out, int n4){
  int i = blockIdx.x*256 + threadIdx.x;
  if (i >= n4) return;
  float4 v = ((const float4*)in)[i];
  ushort4 o;
  o.x = f2h(v.x); o.y = f2h(v.y); o.z = f2h(v.z); o.w = f2h(v.w);
  ((ushort4*)out)[i] = o;
}

// ---------- fused 3-projection GEMM (fp16 MFMA) ----------
// A = x_f16 [M_TOT, IN_SZ] row-major; B^T = U [HID, IN_SZ] row-major.
// 128x128 tile, BK=64, 4 waves each computing a 64x64 quadrant (4x4 MFMA 16x16x32).
// LDS: 16B chunks, chunk(row, o_l) with o_l = o_g ^ (row&7) (XOR swizzle: ds_read_b128
// fragment reads hit all 32 banks evenly).
// z=0 -> pc (fp16 ws), z=1 -> pa (fp16 ws), z=2 -> ph (fp16 ws if phsep, else fp32 y).
__global__ __launch_bounds__(256) void gemm3(
    const unsigned short* __restrict__ xb,
    const unsigned short* __restrict__ U0,
    const unsigned short* __restrict__ U1,
    const unsigned short* __restrict__ U2,
    const float* __restrict__ b0, const float* __restrict__ b1, const float* __restrict__ b2,
    unsigned short* out0, unsigned short* out1, void* out2, int ph_f16)
{
  __shared__ uint4 smem[2048];   // 32 KB: A chunks [0,1024), B chunks [1024,2048)
  const int tid  = threadIdx.x;
  const int wave = tid >> 6, lane = tid & 63;
  const int quad = lane >> 4, l16 = lane & 15;
  const int nb = blockIdx.x;   // 0..7
  const int mb = blockIdx.y;   // 0..255
  const int z  = blockIdx.z;   // 0..2
  const int m0 = mb * 128, n0 = nb * 128;
  const unsigned short* Um = (z==0) ? U0 : (z==1) ? U1 : U2;
  const float* bias        = (z==0) ? b0 : (z==1) ? b1 : b2;
  const int wm = wave >> 1, wn = wave & 1;

  const f32x4 zf = {0.f, 0.f, 0.f, 0.f};
  f32x4 acc[4][4];
#pragma unroll
  for (int i=0;i<4;i++)
#pragma unroll
    for (int j=0;j<4;j++) acc[i][j] = zf;

  const uint4* ldsA = smem;
  const uint4* ldsB = smem + 1024;

  for (int k0 = 0; k0 < IN_SZ; k0 += 64) {
#pragma unroll
    for (int j = 0; j < 4; j++) {
      int c   = (wave*4 + j)*64 + lane;
      int row = c >> 3;
      int og  = (c & 7) ^ (row & 7);
      const unsigned short* ga = xb + (size_t)(m0 + row)*IN_SZ + k0 + og*8;
      const unsigned short* gb = Um + (size_t)(n0 + row)*IN_SZ + k0 + og*8;
      async16(ga, (void*)(smem + (size_t)(wave*4 + j)*64));
      async16(gb, (void*)(smem + 1024 + (size_t)(wave*4 + j)*64));
    }
    __syncthreads();

#pragma unroll
    for (int ks8 = 0; ks8 < 8; ks8 += 4) {   // two K=32 steps
      f16x8 af[4], bfr[4];
#pragma unroll
      for (int im = 0; im < 4; im++){
        int row = wm*64 + im*16 + l16;
        int ch  = row*8 + ((ks8 + quad) ^ (row & 7));
        af[im] = *(const f16x8*)(ldsA + ch);
      }
#pragma unroll
      for (int in = 0; in < 4; in++){
        int row = wn*64 + in*16 + l16;
        int ch  = row*8 + ((ks8 + quad) ^ (row & 7));
        bfr[in] = *(const f16x8*)(ldsB + ch);
      }
#pragma unroll
      for (int im = 0; im < 4; im++)
#pragma unroll
        for (int in = 0; in < 4; in++)
          acc[im][in] = __builtin_amdgcn_mfma_f32_16x16x32_f16(af[im], bfr[in], acc[im][in], 0, 0, 0);
    }
    __syncthreads();
  }

  // epilogue: C/D layout col = lane&15, row = quad*4 + reg
  float bv[4];
#pragma unroll
  for (int in = 0; in < 4; in++) bv[in] = bias[n0 + wn*64 + in*16 + l16];

#pragma unroll
  for (int im = 0; im < 4; im++){
#pragma unroll
    for (int r = 0; r < 4; r++){
      int row = m0 + wm*64 + im*16 + quad*4 + r;
      size_t rb = (size_t)row * HID;
#pragma unroll
      for (int in = 0; in < 4; in++){
        int col = n0 + wn*64 + in*16 + l16;
        float v = acc[im][in][r] + bv[in];
        if (z == 2) {
          if (ph_f16) ((unsigned short*)out2)[rb + col] = f2h(v);
          else        ((float*)out2)[rb + col] = v;
        } else {
          unsigned short* op = (z==0) ? out0 : out1;
          op[rb + col] = f2h(v);
        }
      }
    }
  }
}

// ---------- elementwise recurrence: one thread per (b,h), chunked register pipeline ----
// Chunk of D_CH timesteps double-buffered in named registers (constant indices only —
// no dynamic indexing, so no scratch demotion). Raw loads buffered as-is; fp16->fp32
// conversion deferred to the compute phase so no waitcnt is forced at load time.
template <bool PH16>
__global__ __launch_bounds__(256) void scan_k(
    const unsigned short* __restrict__ pc, const unsigned short* __restrict__ pa,
    const void* __restrict__ phv,
    float* __restrict__ y,
    const float* __restrict__ h0, const float* __restrict__ wc, const float* __restrict__ wa,
    float* __restrict__ hlast)
{
  const int idx  = blockIdx.x * 256 + threadIdx.x;   // 0..65535
  const int hidx = idx & (HID - 1);
  float h = h0[idx];
  const float wcv = wc[hidx], wav = wa[hidx];
  const unsigned short* ph16 = (const unsigned short*)phv;
  const float*          ph32 = (const float*)phv;

  unsigned short cpc[D_CH], cpa[D_CH];
  unsigned short npc[D_CH], npa[D_CH];
  float cph[D_CH], nph[D_CH];
  unsigned short cph16[D_CH], nph16[D_CH];

#pragma unroll
  for (int i = 0; i < D_CH; i++){
    size_t b = (size_t)i*BH + idx;
    cpc[i] = pc[b]; cpa[i] = pa[b];
    if (PH16) cph16[i] = ph16[b]; else cph[i] = ph32[b];
  }

  constexpr int NC = T_SEQ / D_CH;
  for (int c = 0; c < NC; c++){
    const int t0 = c * D_CH;
    if (c + 1 < NC){
#pragma unroll
      for (int i = 0; i < D_CH; i++){
        size_t b = (size_t)(t0 + D_CH + i)*BH + idx;
        npc[i] = pc[b]; npa[i] = pa[b];
        if (PH16) nph16[i] = ph16[b]; else nph[i] = ph32[b];
      }
    }
#pragma unroll
    for (int i = 0; i < D_CH; i++){
      float pcv = h2f(cpc[i]);
      float pav = h2f(cpa[i]);
      float phv_ = PH16 ? h2f(cph16[i]) : cph[i];
      float cc = sigm_f(pcv + wcv*h);
      float a  = 1.f + tanh_f(pav + wav*h);
      float hc = tanh_f(phv_ + a*h);
      h = cc*h + (1.f - cc)*hc;
      y[(size_t)(t0 + i)*BH + idx] = h;
    }
    if (c + 1 < NC){
#pragma unroll
      for (int i = 0; i < D_CH; i++){
        cpc[i] = npc[i]; cpa[i] = npa[i];
        if (PH16) cph16[i] = nph16[i]; else cph[i] = nph[i];
      }
    }
  }
  hlast[idx] = h;
}

extern "C" void kernel_launch(void* const* d_in, const int* in_sizes, int n_in,
                              void* d_out, int out_size, void* d_ws, size_t ws_size,
                              hipStream_t stream)
{
  const float* x  = (const float*)d_in[0];
  const float* h0 = (const float*)d_in[1];
  const float* Uc = (const float*)d_in[2];
  const float* wc = (const float*)d_in[3];
  const float* bc = (const float*)d_in[4];
  const float* Ua = (const float*)d_in[5];
  const float* wa = (const float*)d_in[6];
  const float* ba = (const float*)d_in[7];
  const float* Uh = (const float*)d_in[8];
  const float* bh = (const float*)d_in[9];

  float* y     = (float*)d_out;                 // [T,B,H]
  float* hlast = y + (size_t)T_SEQ * BH;        // [B,H]

  const size_t szP16 = (size_t)T_SEQ * BH * 2;     // 67,108,864 B
  const size_t szX16 = (size_t)M_TOT * IN_SZ * 2;  // 33,554,432 B
  const size_t szU16 = (size_t)HID * IN_SZ * 2;    // 1,048,576 B

  // base layout (guaranteed by round-2 evidence: ws >= 171 MB): pc16, pa16, xb, U0..U2
  const size_t base = 2*szP16 + szX16 + 3*szU16;
  const bool ph_sep = ws_size >= base + szP16;     // room for separate ph16 buffer?

  char* w = (char*)d_ws;
  unsigned short* pc16 = (unsigned short*)w;
  unsigned short* pa16 = (unsigned short*)(w + szP16);
  unsigned short* xb   = (unsigned short*)(w + 2*szP16);
  unsigned short* U0b  = (unsigned short*)(w + 2*szP16 + szX16);
  unsigned short* U1b  = U0b + szU16/2;
  unsigned short* U2b  = U1b + szU16/2;
  unsigned short* ph16 = (unsigned short*)(w + base);   // only used if ph_sep

  // convert inputs to fp16
  {
    int n4 = M_TOT*IN_SZ/4;
    cvt_f16<<<(n4 + 255)/256, 256, 0, stream>>>(x, xb, n4);
    int u4 = HID*IN_SZ/4;
    cvt_f16<<<(u4 + 255)/256, 256, 0, stream>>>(Uc, U0b, u4);
    cvt_f16<<<(u4 + 255)/256, 256, 0, stream>>>(Ua, U1b, u4);
    cvt_f16<<<(u4 + 255)/256, 256, 0, stream>>>(Uh, U2b, u4);
  }

  void* phbuf = ph_sep ? (void*)ph16 : (void*)y;
  gemm3<<<dim3(8, 256, 3), 256, 0, stream>>>(xb, U0b, U1b, U2b, bc, ba, bh,
                                             pc16, pa16, phbuf, ph_sep ? 1 : 0);

  if (ph_sep)
    scan_k<true><<<BH/256, 256, 0, stream>>>(pc16, pa16, (const void*)ph16,
                                             y, h0, wc, wa, hlast);
  else
    scan_k<false><<<BH/256, 256, 0, stream>>>(pc16, pa16, (const void*)y,
                                              y, h0, wc, wa, hlast);
}

// Round 5
// 443.646 us; speedup vs baseline: 1.7603x; 1.0554x over previous
//
#include <hip/hip_runtime.h>
#include <cstdint>
#include <cstddef>

#define T_SEQ 512
#define BATCH 64
#define IN_SZ 512
#define HID   1024
#define BH    (BATCH*HID)      /* 65536 */
#define M_TOT (T_SEQ*BATCH)    /* 32768 */
#define D_CH  16               /* scan chunk depth */

typedef float f32x4 __attribute__((ext_vector_type(4)));
typedef _Float16 f16x8 __attribute__((ext_vector_type(8)));

__device__ inline unsigned short f2h(float f){
  union { _Float16 h; unsigned short u; } v;
  v.h = (_Float16)f;            // RTNE
  return v.u;
}
__device__ inline float h2f(unsigned short s){
  union { unsigned short u; _Float16 h; } v; v.u = s;
  return (float)v.h;
}

__device__ inline float sigm_f(float x){ return 1.f/(1.f + __expf(-x)); }
__device__ inline float tanh_f(float x){ float e = __expf(2.f*x); return 1.f - 2.f/(e + 1.f); }

// async global->LDS, 16B per lane; lds base must be wave-uniform
__device__ inline void async16(const void* g, void* l){
  __builtin_amdgcn_global_load_lds(
      (__attribute__((address_space(1))) void*)g,
      (__attribute__((address_space(3))) void*)l,
      16, 0, 0);
}

// ---------- fused fp32 -> fp16 conversion for x, Uc, Ua, Uh ----------
// x: 4,194,304 float4 -> 16384 blocks; each U: 131,072 float4 -> 512 blocks.
#define XBLK 16384
__global__ __launch_bounds__(256) void cvt_all(
    const float* __restrict__ x,  const float* __restrict__ Uc,
    const float* __restrict__ Ua, const float* __restrict__ Uh,
    unsigned short* __restrict__ xb, unsigned short* __restrict__ U0,
    unsigned short* __restrict__ U1, unsigned short* __restrict__ U2)
{
  int b = blockIdx.x;
  const float* in; unsigned short* out; int i;
  if (b < XBLK){
    in = x; out = xb; i = b*256 + threadIdx.x;
  } else {
    int r = b - XBLK;
    int which = r >> 9;            // 0..2
    int lb = r & 511;
    i = lb*256 + threadIdx.x;
    in  = (which==0) ? Uc : (which==1) ? Ua : Uh;
    out = (which==0) ? U0 : (which==1) ? U1 : U2;
  }
  float4 v = ((const float4*)in)[i];
  ushort4 o;
  o.x = f2h(v.x); o.y = f2h(v.y); o.z = f2h(v.z); o.w = f2h(v.w);
  ((ushort4*)out)[i] = o;
}

// ---------- fused 3-projection GEMM (fp16 MFMA) ----------
// A = x_f16 [M_TOT, IN_SZ]; B^T = U [HID, IN_SZ]. 128x128 tile, BK=64.
// 1D grid, XCD-aware swizzle: xcd = bid&7 owns mb in [xcd*32, xcd*32+32); within a
// slot z (fastest) then nb vary, so 24 consecutive same-XCD slots share one A tile
// (L2-resident) and all three 1MB U's stay hot in that XCD's L2.
// Staging LDS: 16B chunks, chunk(row, o_l) with o_l = o_g ^ (row&7) (XOR swizzle).
// Epilogue: bias+cvt into LDS [128][136] fp16, then coalesced dwordx4 stores.
__global__ __launch_bounds__(256) void gemm3(
    const unsigned short* __restrict__ xb,
    const unsigned short* __restrict__ U0,
    const unsigned short* __restrict__ U1,
    const unsigned short* __restrict__ U2,
    const float* __restrict__ b0, const float* __restrict__ b1, const float* __restrict__ b2,
    unsigned short* out0, unsigned short* out1, void* out2, int ph_f16)
{
  __shared__ __align__(16) unsigned char smem_raw[34816]; // 32KB tiles / 34KB transpose
  uint4* smem = (uint4*)smem_raw;
  unsigned short* strans = (unsigned short*)smem_raw;     // [128][136] fp16

  const int tid  = threadIdx.x;
  const int wave = tid >> 6, lane = tid & 63;
  const int quad = lane >> 4, l16 = lane & 15;

  const int bid  = blockIdx.x;          // 0..6143
  const int xcd  = bid & 7;
  const int slot = bid >> 3;            // 0..767
  const int mbl  = slot / 24;
  const int inner = slot - mbl*24;      // 0..23
  const int mb = xcd*32 + mbl;          // 0..255
  const int z  = inner % 3;
  const int nb = inner / 3;             // 0..7

  const int m0 = mb * 128, n0 = nb * 128;
  const unsigned short* Um = (z==0) ? U0 : (z==1) ? U1 : U2;
  const float* bias        = (z==0) ? b0 : (z==1) ? b1 : b2;
  const int wm = wave >> 1, wn = wave & 1;

  const f32x4 zf = {0.f, 0.f, 0.f, 0.f};
  f32x4 acc[4][4];
#pragma unroll
  for (int i=0;i<4;i++)
#pragma unroll
    for (int j=0;j<4;j++) acc[i][j] = zf;

  const uint4* ldsA = smem;
  const uint4* ldsB = smem + 1024;

  for (int k0 = 0; k0 < IN_SZ; k0 += 64) {
#pragma unroll
    for (int j = 0; j < 4; j++) {
      int c   = (wave*4 + j)*64 + lane;
      int row = c >> 3;
      int og  = (c & 7) ^ (row & 7);
      const unsigned short* ga = xb + (size_t)(m0 + row)*IN_SZ + k0 + og*8;
      const unsigned short* gb = Um + (size_t)(n0 + row)*IN_SZ + k0 + og*8;
      async16(ga, (void*)(smem + (size_t)(wave*4 + j)*64));
      async16(gb, (void*)(smem + 1024 + (size_t)(wave*4 + j)*64));
    }
    __syncthreads();

#pragma unroll
    for (int ks8 = 0; ks8 < 8; ks8 += 4) {   // two K=32 steps
      f16x8 af[4], bfr[4];
#pragma unroll
      for (int im = 0; im < 4; im++){
        int row = wm*64 + im*16 + l16;
        int ch  = row*8 + ((ks8 + quad) ^ (row & 7));
        af[im] = *(const f16x8*)(ldsA + ch);
      }
#pragma unroll
      for (int in = 0; in < 4; in++){
        int row = wn*64 + in*16 + l16;
        int ch  = row*8 + ((ks8 + quad) ^ (row & 7));
        bfr[in] = *(const f16x8*)(ldsB + ch);
      }
#pragma unroll
      for (int im = 0; im < 4; im++)
#pragma unroll
        for (int in = 0; in < 4; in++)
          acc[im][in] = __builtin_amdgcn_mfma_f32_16x16x32_f16(af[im], bfr[in], acc[im][in], 0, 0, 0);
    }
    __syncthreads();
  }

  // epilogue: C/D layout col = lane&15, row = quad*4 + reg
  float bv[4];
#pragma unroll
  for (int in = 0; in < 4; in++) bv[in] = bias[n0 + wn*64 + in*16 + l16];

  if (z == 2 && !ph_f16) {
    // fp32 fallback: direct scalar stores
    float* o32 = (float*)out2;
#pragma unroll
    for (int im = 0; im < 4; im++)
#pragma unroll
      for (int r = 0; r < 4; r++){
        int row = m0 + wm*64 + im*16 + quad*4 + r;
        size_t rb = (size_t)row * HID;
#pragma unroll
        for (int in = 0; in < 4; in++)
          o32[rb + n0 + wn*64 + in*16 + l16] = acc[im][in][r] + bv[in];
      }
    return;
  }

  unsigned short* op = (z==0) ? out0 : (z==1) ? out1 : (unsigned short*)out2;
  const int RS = 136;   // row stride in ushorts (272B: 16B-aligned rows)
  // phase 1: bias + cvt into LDS
#pragma unroll
  for (int im = 0; im < 4; im++)
#pragma unroll
    for (int r = 0; r < 4; r++){
      int row = wm*64 + im*16 + quad*4 + r;
#pragma unroll
      for (int in = 0; in < 4; in++){
        int col = wn*64 + in*16 + l16;
        strans[row*RS + col] = f2h(acc[im][in][r] + bv[in]);
      }
    }
  __syncthreads();
  // phase 2: coalesced dwordx4 stores (256 B contiguous per 16-lane group)
#pragma unroll
  for (int p = 0; p < 8; p++){
    int row = (tid >> 4) + p*16;
    int c8  = tid & 15;
    uint4 v = *(const uint4*)(strans + row*RS + c8*8);
    *(uint4*)(op + (size_t)(m0 + row)*HID + n0 + c8*8) = v;
  }
}

// ---------- elementwise recurrence: one thread per (b,h), chunked register pipeline ----
template <bool PH16>
__global__ __launch_bounds__(256) void scan_k(
    const unsigned short* __restrict__ pc, const unsigned short* __restrict__ pa,
    const void* __restrict__ phv,
    float* __restrict__ y,
    const float* __restrict__ h0, const float* __restrict__ wc, const float* __restrict__ wa,
    float* __restrict__ hlast)
{
  const int idx  = blockIdx.x * 256 + threadIdx.x;   // 0..65535
  const int hidx = idx & (HID - 1);
  float h = h0[idx];
  const float wcv = wc[hidx], wav = wa[hidx];
  const unsigned short* ph16 = (const unsigned short*)phv;
  const float*          ph32 = (const float*)phv;

  unsigned short cpc[D_CH], cpa[D_CH];
  unsigned short npc[D_CH], npa[D_CH];
  float cph[D_CH], nph[D_CH];
  unsigned short cph16[D_CH], nph16[D_CH];

#pragma unroll
  for (int i = 0; i < D_CH; i++){
    size_t b = (size_t)i*BH + idx;
    cpc[i] = pc[b]; cpa[i] = pa[b];
    if (PH16) cph16[i] = ph16[b]; else cph[i] = ph32[b];
  }

  constexpr int NC = T_SEQ / D_CH;
  for (int c = 0; c < NC; c++){
    const int t0 = c * D_CH;
    if (c + 1 < NC){
#pragma unroll
      for (int i = 0; i < D_CH; i++){
        size_t b = (size_t)(t0 + D_CH + i)*BH + idx;
        npc[i] = pc[b]; npa[i] = pa[b];
        if (PH16) nph16[i] = ph16[b]; else nph[i] = ph32[b];
      }
    }
#pragma unroll
    for (int i = 0; i < D_CH; i++){
      float pcv = h2f(cpc[i]);
      float pav = h2f(cpa[i]);
      float phv_ = PH16 ? h2f(cph16[i]) : cph[i];
      float cc = sigm_f(pcv + wcv*h);
      float a  = 1.f + tanh_f(pav + wav*h);
      float hc = tanh_f(phv_ + a*h);
      h = cc*h + (1.f - cc)*hc;
      y[(size_t)(t0 + i)*BH + idx] = h;
    }
    if (c + 1 < NC){
#pragma unroll
      for (int i = 0; i < D_CH; i++){
        cpc[i] = npc[i]; cpa[i] = npa[i];
        if (PH16) cph16[i] = nph16[i]; else cph[i] = nph[i];
      }
    }
  }
  hlast[idx] = h;
}

extern "C" void kernel_launch(void* const* d_in, const int* in_sizes, int n_in,
                              void* d_out, int out_size, void* d_ws, size_t ws_size,
                              hipStream_t stream)
{
  const float* x  = (const float*)d_in[0];
  const float* h0 = (const float*)d_in[1];
  const float* Uc = (const float*)d_in[2];
  const float* wc = (const float*)d_in[3];
  const float* bc = (const float*)d_in[4];
  const float* Ua = (const float*)d_in[5];
  const float* wa = (const float*)d_in[6];
  const float* ba = (const float*)d_in[7];
  const float* Uh = (const float*)d_in[8];
  const float* bh = (const float*)d_in[9];

  float* y     = (float*)d_out;                 // [T,B,H]
  float* hlast = y + (size_t)T_SEQ * BH;        // [B,H]

  const size_t szP16 = (size_t)T_SEQ * BH * 2;     // 67,108,864 B
  const size_t szX16 = (size_t)M_TOT * IN_SZ * 2;  // 33,554,432 B
  const size_t szU16 = (size_t)HID * IN_SZ * 2;    // 1,048,576 B

  const size_t base = 2*szP16 + szX16 + 3*szU16;
  const bool ph_sep = ws_size >= base + szP16;     // separate fp16 ph buffer?

  char* w = (char*)d_ws;
  unsigned short* pc16 = (unsigned short*)w;
  unsigned short* pa16 = (unsigned short*)(w + szP16);
  unsigned short* xb   = (unsigned short*)(w + 2*szP16);
  unsigned short* U0b  = (unsigned short*)(w + 2*szP16 + szX16);
  unsigned short* U1b  = U0b + szU16/2;
  unsigned short* U2b  = U1b + szU16/2;
  unsigned short* ph16 = (unsigned short*)(w + base);   // only if ph_sep

  cvt_all<<<XBLK + 3*512, 256, 0, stream>>>(x, Uc, Ua, Uh, xb, U0b, U1b, U2b);

  void* phbuf = ph_sep ? (void*)ph16 : (void*)y;
  gemm3<<<6144, 256, 0, stream>>>(xb, U0b, U1b, U2b, bc, ba, bh,
                                  pc16, pa16, phbuf, ph_sep ? 1 : 0);

  if (ph_sep)
    scan_k<true><<<BH/256, 256, 0, stream>>>(pc16, pa16, (const void*)ph16,
                                             y, h0, wc, wa, hlast);
  else
    scan_k<false><<<BH/256, 256, 0, stream>>>(pc16, pa16, (const void*)y,
                                              y, h0, wc, wa, hlast);
}